// Round 8
// baseline (314.184 us; speedup 1.0000x reference)
//
#include <hip/hip_runtime.h>
#include <hip/hip_bf16.h>

#define B_ 16
#define L_ 1024
#define D_ 768
#define H_ 4
#define C_ 256
#define E_ 8192
#define ET_ (E_ + L_)     // 9216 edges per graph incl. self loops
#define HC_ (H_ * C_)     // 1024
#define F_ (D_ + HC_)     // 1792
#define M_ (B_ * L_)      // 16384 total nodes
#define NEG_SLOPE 0.2f

typedef short bf16x8 __attribute__((ext_vector_type(8)));
typedef float f32x16 __attribute__((ext_vector_type(16)));
using bf16 = __hip_bfloat16;

struct bf16x4_s { bf16 x, y, z, w; };

// ---------------- async global->LDS, 16B per lane ----------------
__device__ __forceinline__ void async_copy16(const bf16* gsrc, bf16* ldst) {
  __builtin_amdgcn_global_load_lds(
      (const __attribute__((address_space(1))) unsigned int*)gsrc,
      (__attribute__((address_space(3))) unsigned int*)ldst, 16, 0, 0);
}

// ============ kernel 1: prep — CSR (LDS) + x cast + weight casts + cout ============
#define NB_CSR 16
#define NB_X (M_ * (D_ / 8) / 256)   // 6144: one 8-elem chunk per thread
#define NB_W 2112                     // (HC_*D_ + D_*F_)/4/256 float4 chunks
#define NB_CO 3

__global__ __launch_bounds__(256)
void prep(const float* __restrict__ x, const int* __restrict__ ei,
          const float* __restrict__ Wg, const float* __restrict__ Wout,
          const float* __restrict__ bgat, const float* __restrict__ bout,
          bf16* __restrict__ xf, bf16* __restrict__ wg_bf, bf16* __restrict__ wout_bf,
          int* __restrict__ deg_g, int* __restrict__ offs_g, int* __restrict__ csr_src,
          float* __restrict__ cout)
{
  __shared__ int s_deg[L_];
  __shared__ int s_cur[L_];
  __shared__ int s_part[256];
  const int blk = blockIdx.x;
  const int t = threadIdx.x;

  if (blk < NB_CSR) {
    // ---- whole CSR for graph b in one block: count -> scan -> fill (LDS only) ----
    const int b = blk;
    const int* srcp = ei + (long)b * 2 * E_;
    const int* dstp = srcp + E_;
    for (int i = t; i < L_; i += 256) s_deg[i] = 0;
    __syncthreads();
    for (int e = t; e < ET_; e += 256) {
      int dst = (e < E_) ? dstp[e] : (e - E_);
      atomicAdd(&s_deg[dst], 1);
    }
    __syncthreads();
    int d0 = s_deg[t*4], d1 = s_deg[t*4+1], d2 = s_deg[t*4+2], d3 = s_deg[t*4+3];
    int tsum = d0 + d1 + d2 + d3;
    s_part[t] = tsum;
    __syncthreads();
    for (int o = 1; o < 256; o <<= 1) {
      int v = (t >= o) ? s_part[t - o] : 0;
      __syncthreads();
      s_part[t] += v;
      __syncthreads();
    }
    int run = s_part[t] - tsum;       // exclusive prefix
    int o0 = run, o1 = o0 + d0, o2 = o1 + d1, o3 = o2 + d2;
    s_cur[t*4] = o0; s_cur[t*4+1] = o1; s_cur[t*4+2] = o2; s_cur[t*4+3] = o3;
    int gb = b * L_ + t * 4;
    offs_g[gb] = o0; offs_g[gb+1] = o1; offs_g[gb+2] = o2; offs_g[gb+3] = o3;
    deg_g[gb] = d0; deg_g[gb+1] = d1; deg_g[gb+2] = d2; deg_g[gb+3] = d3;
    __syncthreads();
    int* csr_b = csr_src + (long)b * ET_;
    for (int e = t; e < ET_; e += 256) {
      int src = (e < E_) ? srcp[e] : (e - E_);
      int dst = (e < E_) ? dstp[e] : (e - E_);
      int slot = atomicAdd(&s_cur[dst], 1);
      csr_b[slot] = src;
    }
  } else if (blk < NB_CSR + NB_X) {
    // ---- x cast: one 8-elem chunk per thread into xf cols 0..767 ----
    int idx = (blk - NB_CSR) * 256 + t;
    int row = idx / (D_ / 8);
    int c8 = idx - row * (D_ / 8);
    const float4* src = (const float4*)(x + (long)row * D_ + c8 * 8);
    float4 v0 = src[0], v1 = src[1];
    bf16 o[8];
    o[0] = __float2bfloat16(v0.x); o[1] = __float2bfloat16(v0.y);
    o[2] = __float2bfloat16(v0.z); o[3] = __float2bfloat16(v0.w);
    o[4] = __float2bfloat16(v1.x); o[5] = __float2bfloat16(v1.y);
    o[6] = __float2bfloat16(v1.z); o[7] = __float2bfloat16(v1.w);
    *(uint4*)(xf + (long)row * F_ + c8 * 8) = *(const uint4*)o;
  } else if (blk < NB_CSR + NB_X + NB_W) {
    // ---- weight casts: Wg then Wout, one float4 per thread ----
    long na4 = (long)HC_ * D_ / 4;
    long nb4 = (long)D_ * F_ / 4;
    long i0 = (long)(blk - NB_CSR - NB_X) * 256 + t;
    long stride = (long)NB_W * 256;
    for (long i = i0; i < na4 + nb4; i += stride) {
      const float4 v = (i < na4) ? ((const float4*)Wg)[i] : ((const float4*)Wout)[i - na4];
      bf16x4_s o;
      o.x = __float2bfloat16(v.x);
      o.y = __float2bfloat16(v.y);
      o.z = __float2bfloat16(v.z);
      o.w = __float2bfloat16(v.w);
      if (i < na4) ((bf16x4_s*)wg_bf)[i] = o;
      else         ((bf16x4_s*)wout_bf)[i - na4] = o;
    }
  } else {
    // ---- cout[o] = b_out[o] + sum_j b_gat[j] * W_out[o, D_+j] ----
    int o = (blk - NB_CSR - NB_X - NB_W) * 256 + t;
    if (o < D_) {
      float s = bout[o];
      const float* wrow = Wout + (long)o * F_ + D_;
      for (int j = 0; j < HC_; j++) s += bgat[j] * wrow[j];
      cout[o] = s;
    }
  }
}

// ============ NT GEMM, 128x128 tile, BK=64, 32x32x16 MFMA ============
// Conflict-free LDS layout (no XOR): staging lane mapping row_in_8=lane&7,
// kchunk=lane>>3 gives LDS layout [8-row group][kchunk][row%8][16B]. A fragment
// read's consecutive 8 lanes sweep all 32 banks (bank start = (row&7)*4).
// element offset of (row r, chunk c): (r>>3)*512 + c*64 + (r&7)*8.
// Fragments: A row m=lane&31, k=(lane>>5)*8+j ; B^T row n=lane&31, same k.
// C/D (m74/m101): col=lane&31, row=(reg&3)+8*(reg>>2)+4*(lane>>5), reg in [0,16).
#define BM 128
#define BN 128
#define BK 64

template <int OUT_BF16>
__global__ __launch_bounds__(256)
void gemm_nt_128(const bf16* __restrict__ A, int lda,
                 const bf16* __restrict__ Bm, int ldb,
                 void* __restrict__ Cm_, int ldc, int K,
                 const float* __restrict__ bias)
{
  __shared__ __align__(16) bf16 As[BM * BK];   // 16 KB
  __shared__ __align__(16) bf16 Bs[BN * BK];   // 16 KB
  const int t = threadIdx.x;
  const int lane = t & 63;
  const int wave = t >> 6;
  const long m0 = (long)blockIdx.x * BM;
  const long n0 = (long)blockIdx.y * BN;
  const int wm = (wave >> 1) * 64;
  const int wn = (wave & 1) * 64;
  const int lrow = lane & 31;
  const int kg = lane >> 5;          // 0..1: which 8-elem k block within 16

  const int row8 = lane & 7;         // staging: row within 8-row group
  const int kch  = lane >> 3;        // staging: k-chunk 0..7

  f32x16 acc[2][2] = {};

  for (int k0 = 0; k0 < K; k0 += BK) {
    // wave w stages 8-row groups [w*4, w*4+4) of both tiles
#pragma unroll
    for (int j = 0; j < 4; j++) {
      int grp = wave * 4 + j;
      int r = grp * 8 + row8;
      int col = k0 + kch * 8;
      async_copy16(A + (m0 + r) * lda + col, As + grp * 512);
      async_copy16(Bm + (n0 + r) * ldb + col, Bs + grp * 512);
    }
    __syncthreads();
#pragma unroll
    for (int ks = 0; ks < BK; ks += 16) {
      bf16x8 af[2], bfr[2];
      int ca = (ks >> 3) + kg;
#pragma unroll
      for (int i = 0; i < 2; i++) {
        int ra = wm + i * 32 + lrow;
        af[i] = *(const bf16x8*)(As + (ra >> 3) * 512 + ca * 64 + (ra & 7) * 8);
        int rb = wn + i * 32 + lrow;
        bfr[i] = *(const bf16x8*)(Bs + (rb >> 3) * 512 + ca * 64 + (rb & 7) * 8);
      }
#pragma unroll
      for (int i = 0; i < 2; i++)
#pragma unroll
        for (int j = 0; j < 2; j++)
          acc[i][j] = __builtin_amdgcn_mfma_f32_32x32x16_bf16(af[i], bfr[j], acc[i][j], 0, 0, 0);
    }
    __syncthreads();
  }

#pragma unroll
  for (int i = 0; i < 2; i++) {
#pragma unroll
    for (int j = 0; j < 2; j++) {
      long col = n0 + wn + j * 32 + lrow;
      float bv = bias ? bias[col] : 0.f;
#pragma unroll
      for (int reg = 0; reg < 16; reg++) {
        long row = m0 + wm + i * 32 + (reg & 3) + 8 * (reg >> 2) + 4 * kg;
        float v = acc[i][j][reg] + bv;
        if (OUT_BF16) ((bf16*)Cm_)[row * ldc + col] = __float2bfloat16(v);
        else          ((float*)Cm_)[row * ldc + col] = v;
      }
    }
  }
}

// ============ fused aggregate: one WAVE per (b,dst), single pass ============
// Per edge the wave holds h[src] entirely (16 ch/lane); logit = lrelu(h[src].as + h[dst].ad)
// via per-head 16-lane shfl reductions. No max-subtraction (logits |e|<~2, exp safe fp32).
__device__ inline float lrelu(float v) { return v > 0.f ? v : NEG_SLOPE * v; }

__device__ __forceinline__ void unpack16(uint4 u0, uint4 u1, float* f) {
#pragma unroll
  for (int k = 0; k < 4; k++) {
    unsigned w = ((const unsigned*)&u0)[k];
    f[2 * k]     = __uint_as_float(w << 16);
    f[2 * k + 1] = __uint_as_float(w & 0xffff0000u);
    unsigned w2 = ((const unsigned*)&u1)[k];
    f[8 + 2 * k]     = __uint_as_float(w2 << 16);
    f[8 + 2 * k + 1] = __uint_as_float(w2 & 0xffff0000u);
  }
}

__global__ __launch_bounds__(256)
void gat_aggregate(const int* __restrict__ offs, const int* __restrict__ deg_a,
                   const int* __restrict__ csr_src,
                   const float* __restrict__ att_s_g, const float* __restrict__ att_d_g,
                   const bf16* __restrict__ h, bf16* __restrict__ xg, int ldx)
{
  const int t = threadIdx.x;
  const int lane = t & 63;
  const int wave = t >> 6;
  // XCD swizzle: graph b pinned to XCD b%8 (2 graphs = 4MB h per XCD L2)
  const int i = blockIdx.x;
  const int b = (i & 7) + 8 * ((i >> 3) >> 8);
  const int grp = (i >> 3) & 255;
  const int bd = b * L_ + grp * 4 + wave;
  const int deg = deg_a[bd];
  const int* list = csr_src + (long)b * ET_ + offs[bd];
  const int c0 = lane * 16;            // my 16 channels; head = lane>>4

  float as16[16], ad16[16];
#pragma unroll
  for (int q = 0; q < 4; q++) {
    *(float4*)(as16 + 4 * q) = *(const float4*)(att_s_g + c0 + 4 * q);
    *(float4*)(ad16 + 4 * q) = *(const float4*)(att_d_g + c0 + 4 * q);
  }

  // dst's own att_dst logit part (uniform within my 16-lane head group after reduce)
  const bf16* hrow_d = h + (long)bd * HC_ + c0;
  float fd[16];
  unpack16(*(const uint4*)hrow_d, *(const uint4*)(hrow_d + 8), fd);
  float ad = 0.f;
#pragma unroll
  for (int k = 0; k < 16; k++) ad += fd[k] * ad16[k];
#pragma unroll
  for (int o = 1; o < 16; o <<= 1) ad += __shfl_xor(ad, o);

  float acc[16];
#pragma unroll
  for (int k = 0; k < 16; k++) acc[k] = 0.f;
  float ssum = 0.f;
  const bf16* hb = h + (long)b * L_ * HC_ + c0;

  if (deg <= 64) {
    int s_lane = (lane < deg) ? list[lane] : 0;
#pragma unroll 2
    for (int e = 0; e < deg; e++) {
      int se = __shfl(s_lane, e);
      const bf16* hp = hb + (long)se * HC_;
      uint4 u0 = *(const uint4*)hp;
      uint4 u1 = *(const uint4*)(hp + 8);
      float f[16];
      unpack16(u0, u1, f);
      float ds = 0.f;
#pragma unroll
      for (int k = 0; k < 16; k++) ds += f[k] * as16[k];
#pragma unroll
      for (int o = 1; o < 16; o <<= 1) ds += __shfl_xor(ds, o);
      float p = __expf(lrelu(ds + ad));
      ssum += p;
#pragma unroll
      for (int k = 0; k < 16; k++) acc[k] += p * f[k];
    }
  } else {
    for (int e = 0; e < deg; e++) {
      int se = list[e];
      const bf16* hp = hb + (long)se * HC_;
      uint4 u0 = *(const uint4*)hp;
      uint4 u1 = *(const uint4*)(hp + 8);
      float f[16];
      unpack16(u0, u1, f);
      float ds = 0.f;
#pragma unroll
      for (int k = 0; k < 16; k++) ds += f[k] * as16[k];
#pragma unroll
      for (int o = 1; o < 16; o <<= 1) ds += __shfl_xor(ds, o);
      float p = __expf(lrelu(ds + ad));
      ssum += p;
#pragma unroll
      for (int k = 0; k < 16; k++) acc[k] += p * f[k];
    }
  }

  float rs = 1.f / (ssum + 1e-16f);
  bf16 ov[16];
#pragma unroll
  for (int k = 0; k < 16; k++) ov[k] = __float2bfloat16(acc[k] * rs);
  bf16* op = xg + (long)bd * ldx + c0;
  *(uint4*)op = *(const uint4*)ov;
  *(uint4*)(op + 8) = *(const uint4*)(ov + 8);
}

// ---------------- launch ----------------
extern "C" void kernel_launch(void* const* d_in, const int* in_sizes, int n_in,
                              void* d_out, int out_size, void* d_ws, size_t ws_size,
                              hipStream_t stream) {
  const float* x     = (const float*)d_in[0];
  const int*   ei    = (const int*)d_in[1];
  const float* Wg    = (const float*)d_in[2];
  const float* att_s = (const float*)d_in[3];
  const float* att_d = (const float*)d_in[4];
  const float* bgat  = (const float*)d_in[5];
  const float* Wout  = (const float*)d_in[6];
  const float* bout  = (const float*)d_in[7];
  float* out = (float*)d_out;

  char* ws = (char*)d_ws;
  size_t off = 0;
  auto alloc = [&](size_t bytes) {
    void* p = ws + off;
    off = (off + bytes + 255) & ~(size_t)255;
    return p;
  };
  bf16* xf      = (bf16*)alloc((size_t)M_ * F_ * 2);       // 56 MB: [x | xg] bf16
  bf16* wg_bf   = (bf16*)alloc((size_t)HC_ * D_ * 2);
  bf16* wout_bf = (bf16*)alloc((size_t)D_ * F_ * 2);
  bf16* h_bf    = (bf16*)alloc((size_t)M_ * HC_ * 2);      // 32 MB
  int* deg      = (int*)alloc((size_t)M_ * 4);
  int* offs     = (int*)alloc((size_t)M_ * 4);
  int* csr_src  = (int*)alloc((size_t)B_ * ET_ * 4);
  float* cout   = (float*)alloc((size_t)D_ * 4);

  // 1. prep: CSR + x cast + weight casts + cout — one dispatch
  prep<<<dim3(NB_CSR + NB_X + NB_W + NB_CO), dim3(256), 0, stream>>>(
      x, ei, Wg, Wout, bgat, bout, xf, wg_bf, wout_bf, deg, offs, csr_src, cout);

  // 2. h = x @ Wg^T (bf16 out)   — 128 x 8 = 1024 blocks
  gemm_nt_128<1><<<dim3(M_ / BM, HC_ / BN), dim3(256), 0, stream>>>(
      xf, F_, wg_bf, D_, h_bf, HC_, D_, nullptr);

  // 3. fused logits + softmax + aggregate (wave per node), writes xg columns of xf
  gat_aggregate<<<dim3(M_ / 4), dim3(256), 0, stream>>>(offs, deg, csr_src,
                                                        att_s, att_d, h_bf, xf + D_, F_);

  // 4. out = [x|xg] @ W_out^T + cout   (single K=1792 GEMM) — 128 x 6 = 768 blocks
  gemm_nt_128<0><<<dim3(M_ / BM, D_ / BN), dim3(256), 0, stream>>>(
      xf, F_, wout_bf, F_, out, D_, F_, cout);
}

// Round 10
// 259.444 us; speedup vs baseline: 1.2110x; 1.2110x over previous
//
#include <hip/hip_runtime.h>
#include <hip/hip_bf16.h>

#define B_ 16
#define L_ 1024
#define D_ 768
#define H_ 4
#define C_ 256
#define E_ 8192
#define ET_ (E_ + L_)     // 9216 edges per graph incl. self loops
#define HC_ (H_ * C_)     // 1024
#define F_ (D_ + HC_)     // 1792
#define M_ (B_ * L_)      // 16384 total nodes
#define NEG_SLOPE 0.2f

typedef short bf16x8 __attribute__((ext_vector_type(8)));
typedef float f32x16 __attribute__((ext_vector_type(16)));
using bf16 = __hip_bfloat16;

struct bf16x4_s { bf16 x, y, z, w; };

// ---------------- async global->LDS, 16B per lane ----------------
__device__ __forceinline__ void async_copy16(const bf16* gsrc, bf16* ldst) {
  __builtin_amdgcn_global_load_lds(
      (const __attribute__((address_space(1))) unsigned int*)gsrc,
      (__attribute__((address_space(3))) unsigned int*)ldst, 16, 0, 0);
}

// ============ kernel 1: prep — CSR (LDS) + x cast + weight casts + cout ============
#define NB_CSR 16
#define NB_X (M_ * (D_ / 8) / 256)   // 6144: one 8-elem chunk per thread
#define NB_W 2112                     // (HC_*D_ + D_*F_)/4/256 float4 chunks
#define NB_CO 3

__global__ __launch_bounds__(256)
void prep(const float* __restrict__ x, const int* __restrict__ ei,
          const float* __restrict__ Wg, const float* __restrict__ Wout,
          const float* __restrict__ bgat, const float* __restrict__ bout,
          bf16* __restrict__ xf, bf16* __restrict__ wg_bf, bf16* __restrict__ wout_bf,
          int* __restrict__ deg_g, int* __restrict__ offs_g, int* __restrict__ csr_src,
          float* __restrict__ cout)
{
  __shared__ int s_deg[L_];
  __shared__ int s_cur[L_];
  __shared__ int s_part[256];
  const int blk = blockIdx.x;
  const int t = threadIdx.x;

  if (blk < NB_CSR) {
    // ---- whole CSR for graph b in one block: count -> scan -> fill (LDS only) ----
    const int b = blk;
    const int* srcp = ei + (long)b * 2 * E_;
    const int* dstp = srcp + E_;
    for (int i = t; i < L_; i += 256) s_deg[i] = 0;
    __syncthreads();
    for (int e = t; e < ET_; e += 256) {
      int dst = (e < E_) ? dstp[e] : (e - E_);
      atomicAdd(&s_deg[dst], 1);
    }
    __syncthreads();
    int d0 = s_deg[t*4], d1 = s_deg[t*4+1], d2 = s_deg[t*4+2], d3 = s_deg[t*4+3];
    int tsum = d0 + d1 + d2 + d3;
    s_part[t] = tsum;
    __syncthreads();
    for (int o = 1; o < 256; o <<= 1) {
      int v = (t >= o) ? s_part[t - o] : 0;
      __syncthreads();
      s_part[t] += v;
      __syncthreads();
    }
    int run = s_part[t] - tsum;       // exclusive prefix
    int o0 = run, o1 = o0 + d0, o2 = o1 + d1, o3 = o2 + d2;
    s_cur[t*4] = o0; s_cur[t*4+1] = o1; s_cur[t*4+2] = o2; s_cur[t*4+3] = o3;
    int gb = b * L_ + t * 4;
    offs_g[gb] = o0; offs_g[gb+1] = o1; offs_g[gb+2] = o2; offs_g[gb+3] = o3;
    deg_g[gb] = d0; deg_g[gb+1] = d1; deg_g[gb+2] = d2; deg_g[gb+3] = d3;
    __syncthreads();
    int* csr_b = csr_src + (long)b * ET_;
    for (int e = t; e < ET_; e += 256) {
      int src = (e < E_) ? srcp[e] : (e - E_);
      int dst = (e < E_) ? dstp[e] : (e - E_);
      int slot = atomicAdd(&s_cur[dst], 1);
      csr_b[slot] = src;
    }
  } else if (blk < NB_CSR + NB_X) {
    // ---- x cast: one 8-elem chunk per thread into xf cols 0..767 ----
    int idx = (blk - NB_CSR) * 256 + t;
    int row = idx / (D_ / 8);
    int c8 = idx - row * (D_ / 8);
    const float4* src = (const float4*)(x + (long)row * D_ + c8 * 8);
    float4 v0 = src[0], v1 = src[1];
    bf16 o[8];
    o[0] = __float2bfloat16(v0.x); o[1] = __float2bfloat16(v0.y);
    o[2] = __float2bfloat16(v0.z); o[3] = __float2bfloat16(v0.w);
    o[4] = __float2bfloat16(v1.x); o[5] = __float2bfloat16(v1.y);
    o[6] = __float2bfloat16(v1.z); o[7] = __float2bfloat16(v1.w);
    *(uint4*)(xf + (long)row * F_ + c8 * 8) = *(const uint4*)o;
  } else if (blk < NB_CSR + NB_X + NB_W) {
    // ---- weight casts: Wg then Wout, one float4 per thread ----
    long na4 = (long)HC_ * D_ / 4;
    long nb4 = (long)D_ * F_ / 4;
    long i0 = (long)(blk - NB_CSR - NB_X) * 256 + t;
    long stride = (long)NB_W * 256;
    for (long i = i0; i < na4 + nb4; i += stride) {
      const float4 v = (i < na4) ? ((const float4*)Wg)[i] : ((const float4*)Wout)[i - na4];
      bf16x4_s o;
      o.x = __float2bfloat16(v.x);
      o.y = __float2bfloat16(v.y);
      o.z = __float2bfloat16(v.z);
      o.w = __float2bfloat16(v.w);
      if (i < na4) ((bf16x4_s*)wg_bf)[i] = o;
      else         ((bf16x4_s*)wout_bf)[i - na4] = o;
    }
  } else {
    // ---- cout[o] = b_out[o] + sum_j b_gat[j] * W_out[o, D_+j] ----
    int o = (blk - NB_CSR - NB_X - NB_W) * 256 + t;
    if (o < D_) {
      float s = bout[o];
      const float* wrow = Wout + (long)o * F_ + D_;
      for (int j = 0; j < HC_; j++) s += bgat[j] * wrow[j];
      cout[o] = s;
    }
  }
}

// ============ NT GEMM, 128x128 tile, BK=64, 32x32x16 MFMA (validated round-6 config) ============
// global_load_lds 16B staging (8 consecutive lanes = 128B contiguous of one row)
// + XOR swizzle of k-chunks applied on the GLOBAL address, compensated at ds_read.
// K stays a RUNTIME arg: the rolled K-loop's conservative vmcnt(0)-before-barrier is
// load-bearing for correctness (template-K full unroll raced in round 9 — do not redo).
// Fragments: A row m=lane&31, k=(lane>>5)*8+j ; B^T row n=lane&31, same k.
// C/D (m74/m101): col=lane&31, row=(reg&3)+8*(reg>>2)+4*(lane>>5), reg in [0,16).
#define BM 128
#define BN 128
#define BK 64

template <int OUT_BF16>
__global__ __launch_bounds__(256)
void gemm_nt_128(const bf16* __restrict__ A, int lda,
                 const bf16* __restrict__ Bm, int ldb,
                 void* __restrict__ Cm_, int ldc, int K,
                 const float* __restrict__ bias)
{
  __shared__ __align__(16) bf16 As[BM * BK];   // 16 KB
  __shared__ __align__(16) bf16 Bs[BN * BK];   // 16 KB
  const int t = threadIdx.x;
  const int lane = t & 63;
  const int wave = t >> 6;
  const long m0 = (long)blockIdx.x * BM;
  const long n0 = (long)blockIdx.y * BN;
  const int wm = (wave >> 1) * 64;
  const int wn = (wave & 1) * 64;
  const int lrow = lane & 31;
  const int kg = lane >> 5;          // 0..1: which 8-elem k block within 16

  const int sr_base = wave * 32;
  const int sr_lane = lane >> 3;     // 0..7 (8 consecutive lanes share a row)
  const int c8l = lane & 7;          // 0..7

  f32x16 acc[2][2] = {};

  for (int k0 = 0; k0 < K; k0 += BK) {
#pragma unroll
    for (int j = 0; j < 4; j++) {
      int r = sr_base + j * 8 + sr_lane;
      int col = k0 + ((c8l ^ (r & 7)) << 3);
      bf16* ldsA = As + (sr_base + j * 8) * BK;   // wave-uniform base
      bf16* ldsB = Bs + (sr_base + j * 8) * BK;
      async_copy16(A + (m0 + r) * lda + col, ldsA);
      async_copy16(Bm + (n0 + r) * ldb + col, ldsB);
    }
    __syncthreads();
#pragma unroll
    for (int ks = 0; ks < BK; ks += 16) {
      bf16x8 af[2], bfr[2];
#pragma unroll
      for (int i = 0; i < 2; i++) {
        int ra = wm + i * 32 + lrow;
        int ca = ((ks >> 3) + kg) ^ (ra & 7);
        af[i] = *(const bf16x8*)(As + ra * BK + ca * 8);
        int rb = wn + i * 32 + lrow;
        int cb = ((ks >> 3) + kg) ^ (rb & 7);
        bfr[i] = *(const bf16x8*)(Bs + rb * BK + cb * 8);
      }
#pragma unroll
      for (int i = 0; i < 2; i++)
#pragma unroll
        for (int j = 0; j < 2; j++)
          acc[i][j] = __builtin_amdgcn_mfma_f32_32x32x16_bf16(af[i], bfr[j], acc[i][j], 0, 0, 0);
    }
    __syncthreads();
  }

#pragma unroll
  for (int i = 0; i < 2; i++) {
#pragma unroll
    for (int j = 0; j < 2; j++) {
      long col = n0 + wn + j * 32 + lrow;
      float bv = bias ? bias[col] : 0.f;
#pragma unroll
      for (int reg = 0; reg < 16; reg++) {
        long row = m0 + wm + i * 32 + (reg & 3) + 8 * (reg >> 2) + 4 * kg;
        float v = acc[i][j][reg] + bv;
        if (OUT_BF16) ((bf16*)Cm_)[row * ldc + col] = __float2bfloat16(v);
        else          ((float*)Cm_)[row * ldc + col] = v;
      }
    }
  }
}

// ============ fused aggregate: one WAVE per (b,dst), single pass ============
// Per edge the wave holds h[src] entirely (16 ch/lane); logit = lrelu(h[src].as + h[dst].ad)
// via per-head 16-lane shfl reductions. No max-subtraction (logits |e|<~2, exp safe fp32).
__device__ inline float lrelu(float v) { return v > 0.f ? v : NEG_SLOPE * v; }

__device__ __forceinline__ void unpack16(uint4 u0, uint4 u1, float* f) {
#pragma unroll
  for (int k = 0; k < 4; k++) {
    unsigned w = ((const unsigned*)&u0)[k];
    f[2 * k]     = __uint_as_float(w << 16);
    f[2 * k + 1] = __uint_as_float(w & 0xffff0000u);
    unsigned w2 = ((const unsigned*)&u1)[k];
    f[8 + 2 * k]     = __uint_as_float(w2 << 16);
    f[8 + 2 * k + 1] = __uint_as_float(w2 & 0xffff0000u);
  }
}

__global__ __launch_bounds__(256)
void gat_aggregate(const int* __restrict__ offs, const int* __restrict__ deg_a,
                   const int* __restrict__ csr_src,
                   const float* __restrict__ att_s_g, const float* __restrict__ att_d_g,
                   const bf16* __restrict__ h, bf16* __restrict__ xg, int ldx)
{
  const int t = threadIdx.x;
  const int lane = t & 63;
  const int wave = t >> 6;
  // XCD swizzle: graph b pinned to XCD b%8 (2 graphs = 4MB h per XCD L2)
  const int i = blockIdx.x;
  const int b = (i & 7) + 8 * ((i >> 3) >> 8);
  const int grp = (i >> 3) & 255;
  const int bd = b * L_ + grp * 4 + wave;
  const int deg = deg_a[bd];
  const int* list = csr_src + (long)b * ET_ + offs[bd];
  const int c0 = lane * 16;            // my 16 channels; head = lane>>4

  float as16[16], ad16[16];
#pragma unroll
  for (int q = 0; q < 4; q++) {
    *(float4*)(as16 + 4 * q) = *(const float4*)(att_s_g + c0 + 4 * q);
    *(float4*)(ad16 + 4 * q) = *(const float4*)(att_d_g + c0 + 4 * q);
  }

  // dst's own att_dst logit part (uniform within my 16-lane head group after reduce)
  const bf16* hrow_d = h + (long)bd * HC_ + c0;
  float fd[16];
  unpack16(*(const uint4*)hrow_d, *(const uint4*)(hrow_d + 8), fd);
  float ad = 0.f;
#pragma unroll
  for (int k = 0; k < 16; k++) ad += fd[k] * ad16[k];
#pragma unroll
  for (int o = 1; o < 16; o <<= 1) ad += __shfl_xor(ad, o);

  float acc[16];
#pragma unroll
  for (int k = 0; k < 16; k++) acc[k] = 0.f;
  float ssum = 0.f;
  const bf16* hb = h + (long)b * L_ * HC_ + c0;

  if (deg <= 64) {
    int s_lane = (lane < deg) ? list[lane] : 0;
#pragma unroll 2
    for (int e = 0; e < deg; e++) {
      int se = __shfl(s_lane, e);
      const bf16* hp = hb + (long)se * HC_;
      uint4 u0 = *(const uint4*)hp;
      uint4 u1 = *(const uint4*)(hp + 8);
      float f[16];
      unpack16(u0, u1, f);
      float ds = 0.f;
#pragma unroll
      for (int k = 0; k < 16; k++) ds += f[k] * as16[k];
#pragma unroll
      for (int o = 1; o < 16; o <<= 1) ds += __shfl_xor(ds, o);
      float p = __expf(lrelu(ds + ad));
      ssum += p;
#pragma unroll
      for (int k = 0; k < 16; k++) acc[k] += p * f[k];
    }
  } else {
    for (int e = 0; e < deg; e++) {
      int se = list[e];
      const bf16* hp = hb + (long)se * HC_;
      uint4 u0 = *(const uint4*)hp;
      uint4 u1 = *(const uint4*)(hp + 8);
      float f[16];
      unpack16(u0, u1, f);
      float ds = 0.f;
#pragma unroll
      for (int k = 0; k < 16; k++) ds += f[k] * as16[k];
#pragma unroll
      for (int o = 1; o < 16; o <<= 1) ds += __shfl_xor(ds, o);
      float p = __expf(lrelu(ds + ad));
      ssum += p;
#pragma unroll
      for (int k = 0; k < 16; k++) acc[k] += p * f[k];
    }
  }

  float rs = 1.f / (ssum + 1e-16f);
  bf16 ov[16];
#pragma unroll
  for (int k = 0; k < 16; k++) ov[k] = __float2bfloat16(acc[k] * rs);
  bf16* op = xg + (long)bd * ldx + c0;
  *(uint4*)op = *(const uint4*)ov;
  *(uint4*)(op + 8) = *(const uint4*)(ov + 8);
}

// ---------------- launch ----------------
extern "C" void kernel_launch(void* const* d_in, const int* in_sizes, int n_in,
                              void* d_out, int out_size, void* d_ws, size_t ws_size,
                              hipStream_t stream) {
  const float* x     = (const float*)d_in[0];
  const int*   ei    = (const int*)d_in[1];
  const float* Wg    = (const float*)d_in[2];
  const float* att_s = (const float*)d_in[3];
  const float* att_d = (const float*)d_in[4];
  const float* bgat  = (const float*)d_in[5];
  const float* Wout  = (const float*)d_in[6];
  const float* bout  = (const float*)d_in[7];
  float* out = (float*)d_out;

  char* ws = (char*)d_ws;
  size_t off = 0;
  auto alloc = [&](size_t bytes) {
    void* p = ws + off;
    off = (off + bytes + 255) & ~(size_t)255;
    return p;
  };
  bf16* xf      = (bf16*)alloc((size_t)M_ * F_ * 2);       // 56 MB: [x | xg] bf16
  bf16* wg_bf   = (bf16*)alloc((size_t)HC_ * D_ * 2);
  bf16* wout_bf = (bf16*)alloc((size_t)D_ * F_ * 2);
  bf16* h_bf    = (bf16*)alloc((size_t)M_ * HC_ * 2);      // 32 MB
  int* deg      = (int*)alloc((size_t)M_ * 4);
  int* offs     = (int*)alloc((size_t)M_ * 4);
  int* csr_src  = (int*)alloc((size_t)B_ * ET_ * 4);
  float* cout   = (float*)alloc((size_t)D_ * 4);

  // 1. prep: CSR + x cast + weight casts + cout — one dispatch
  prep<<<dim3(NB_CSR + NB_X + NB_W + NB_CO), dim3(256), 0, stream>>>(
      x, ei, Wg, Wout, bgat, bout, xf, wg_bf, wout_bf, deg, offs, csr_src, cout);

  // 2. h = x @ Wg^T (bf16 out)   — 128 x 8 = 1024 blocks
  gemm_nt_128<1><<<dim3(M_ / BM, HC_ / BN), dim3(256), 0, stream>>>(
      xf, F_, wg_bf, D_, h_bf, HC_, D_, nullptr);

  // 3. fused logits + softmax + aggregate (wave per node), writes xg columns of xf
  gat_aggregate<<<dim3(M_ / 4), dim3(256), 0, stream>>>(offs, deg, csr_src,
                                                        att_s, att_d, h_bf, xf + D_, F_);

  // 4. out = [x|xg] @ W_out^T + cout   (single K=1792 GEMM) — 128 x 6 = 768 blocks
  gemm_nt_128<0><<<dim3(M_ / BM, D_ / BN), dim3(256), 0, stream>>>(
      xf, F_, wout_bf, F_, out, D_, F_, cout);
}